// Round 10
// baseline (412.818 us; speedup 1.0000x reference)
//
#include <hip/hip_runtime.h>
#include <hip/hip_bf16.h>
#include <math.h>

// Swin Transformer 3D block, MI355X (gfx950).  R10: strip-ownership fused.
// Wave s owns token strip s end-to-end. LDS 49.8KB -> 3 blocks/CU. 4 barriers.
// Region A: XS -> K (in-place) -> XS2.  Region B: QB -> vT -> resB(bf16).
// Attn-out stays in registers (swapped PV + p-transform feeds proj directly).

#define NTOK 98
#define SCALE 0.17677669529663687f

// fragment ids (x512 elems): qkv 0..53, proj 54..71, fc1 72..143, fc2 144..215
#define FR_PROJ 54
#define FR_FC1  72
#define FR_FC2  144
#define WS_BF16_N 110592
#define WS_BIASM_BYTE 221184
#define WS_NEED   296448

typedef __attribute__((ext_vector_type(8))) short bf16x8;
typedef __attribute__((ext_vector_type(4))) float f32x4;

__device__ __forceinline__ int row_of(int wid, int t) {
    int b = wid >> 8, rem = wid & 255;
    int d0 = rem >> 6, h0 = (rem >> 3) & 7, w0 = rem & 7;
    int td = t / 49, tr = t % 49, th = tr / 7, tw = tr % 7;
    int dd = d0 * 2 + td, hh = h0 * 7 + th, ww = w0 * 7 + tw;
    return ((b * 8 + dd) * 56 + hh) * 56 + ww;
}

__device__ __forceinline__ int pcode(int t) {
    int a = t / 49, r = t - 49 * a, b = r / 7, c = r - 7 * b;
    return a * 169 + b * 13 + c;
}

__device__ __forceinline__ unsigned short f2bfu(float f) {
    __hip_bfloat16 h = __float2bfloat16(f);
    unsigned short u; __builtin_memcpy(&u, &h, 2); return u;
}
__device__ __forceinline__ unsigned int pk2(float lo, float hi) {
    return (unsigned int)f2bfu(lo) | ((unsigned int)f2bfu(hi) << 16);
}
__device__ __forceinline__ float bl16(unsigned int u) {
    union { unsigned int i; float f; } c; c.i = u << 16; return c.f;
}
__device__ __forceinline__ float bh16(unsigned int u) {
    union { unsigned int i; float f; } c; c.i = u & 0xffff0000u; return c.f;
}
__device__ __forceinline__ bf16x8 loadB_sw(const __hip_bfloat16* wsb, int frag, int lane) {
    return *(const bf16x8*)(wsb + (frag << 9) + (lane << 3));
}
__device__ __forceinline__ bf16x8 loadB_f32(const float* wf, int idx) {
    bf16x8 r;
    #pragma unroll
    for (int j = 0; j < 8; ++j) r[j] = (short)f2bfu(wf[idx + j]);
    return r;
}
__device__ __forceinline__ float gelu(float v) {
    return 0.5f * v * (1.f + erff(v * 0.70710678118654752f));
}

// ---------------------------------------------------------------- prep
__global__ __launch_bounds__(256) void prep_kernel(
    const float* __restrict__ qkv_w, const float* __restrict__ proj_w,
    const float* __restrict__ fc1_w, const float* __restrict__ fc2_w,
    const float* __restrict__ rpb,
    __hip_bfloat16* __restrict__ wsb, __hip_bfloat16* __restrict__ biasMb)
{
    int i = blockIdx.x * 256 + threadIdx.x;
    if (i < WS_BF16_N) {
        int f = i >> 9, lane = (i >> 3) & 63, j = i & 7;
        int l15 = lane & 15, g = lane >> 4;
        float v;
        if (f < FR_PROJ) {
            int ks = f % 3, nt = (f / 3) % 6, c = f / 18;
            v = qkv_w[(c * 96 + nt * 16 + l15) * 96 + ks * 32 + g * 8 + j];
            if (c == 0) v *= SCALE;
        } else if (f < FR_FC1) {
            int f2 = f - FR_PROJ, ks = f2 % 3, nt = f2 / 3;
            v = proj_w[(nt * 16 + l15) * 96 + ks * 32 + g * 8 + j];
        } else if (f < FR_FC2) {
            int f2 = f - FR_FC1, ks = f2 % 3, nt = (f2 / 3) % 4, hc = f2 / 12;
            v = fc1_w[(hc * 64 + nt * 16 + l15) * 96 + ks * 32 + g * 8 + j];
        } else {
            int f2 = f - FR_FC2, p = f2 & 1, nt = (f2 >> 1) % 6, hc = f2 / 12;
            v = fc2_w[(nt * 16 + l15) * 384 + hc * 64 + p * 32 + g * 8 + j];
        }
        wsb[i] = __float2bfloat16(v);
    } else if (i < WS_BF16_N + 37632) {
        int j = i - WS_BF16_N;
        int r = j & 3, lane = (j >> 2) & 63;
        int rest = j >> 8;
        int U = rest % 7; rest /= 7;
        int Tt = rest % 7, h = rest / 7;
        int t = Tt * 16 + (lane & 15);              if (t > 97) t = 97;
        int u = U * 16 + ((lane >> 4) << 2) + r;    if (u > 97) u = 97;
        biasMb[j] = __float2bfloat16(rpb[(pcode(t) - pcode(u) + 253) * 3 + h]);
    }
}

// ---------------------------------------------------------------- fused block
__global__ __launch_bounds__(448, 6) void fused_kernel(
    const float* __restrict__ x,
    const float* __restrict__ n1w, const float* __restrict__ n1b,
    const float* __restrict__ qkv_w, const float* __restrict__ qkv_b,
    const float* __restrict__ proj_w, const float* __restrict__ proj_b,
    const float* __restrict__ rpb,
    const float* __restrict__ n2w, const float* __restrict__ n2b,
    const float* __restrict__ w1, const float* __restrict__ b1,
    const float* __restrict__ w2, const float* __restrict__ b2,
    const __hip_bfloat16* __restrict__ wsb, const __hip_bfloat16* __restrict__ biasMb,
    int usews,
    float* __restrict__ out)
{
    // Region A [0,23296): XS bf16[112][104] -> K (in-place) -> XS2
    // Region B [23296,49408): QB[112][104] -> vT[96][136] -> resB[112][104]
    __shared__ __align__(16) unsigned char LB[49408];
    __shared__ int rowbase[NTOK];
    __hip_bfloat16 (*XS)[104] = (__hip_bfloat16 (*)[104])LB;
    __hip_bfloat16* RB = (__hip_bfloat16*)(LB + 23296);

    const int wid = blockIdx.x, tid = threadIdx.x;
    const int lane = tid & 63, wv = tid >> 6;       // 7 waves; wave = strip
    const int l15 = lane & 15;
    const int g = lane >> 4;
    const int koff = g * 8;
    const int drow = g * 4;
    const bool oddg = (g >> 1) & 1;
    const int srcA = l15 + ((g & 1) << 5);
    const int srcB = srcA + 16;
    const int m0 = wv * 16;

    for (int t = tid; t < NTOK; t += 448) rowbase[t] = row_of(wid, t) * 96;
    for (int i = tid; i < 14 * 104; i += 448) {     // zero XS pad rows 98..111
        int r = 98 + i / 104, c = i % 104;
        XS[r][c] = __float2bfloat16(0.f);
    }

    // ---- LN1 -> XS bf16 (one wave per token; 14 tokens/wave exact)
    {
        float w0 = n1w[lane], b0 = n1b[lane];
        float w1_ = (lane < 32) ? n1w[64 + lane] : 0.f;
        float b1_ = (lane < 32) ? n1b[64 + lane] : 0.f;
        for (int t = wv; t < NTOK; t += 7) {
            int base = row_of(wid, t) * 96;
            float v0 = x[base + lane];
            float v1 = (lane < 32) ? x[base + 64 + lane] : 0.f;
            float s = v0 + v1;
            #pragma unroll
            for (int m = 32; m; m >>= 1) s += __shfl_xor(s, m, 64);
            float mean = s * (1.f / 96.f);
            float e0 = v0 - mean;
            float e1 = (lane < 32) ? (v1 - mean) : 0.f;
            float ss = e0 * e0 + e1 * e1;
            #pragma unroll
            for (int m = 32; m; m >>= 1) ss += __shfl_xor(ss, m, 64);
            float rstd = rsqrtf(ss * (1.f / 96.f) + 1e-5f);
            XS[t][lane] = __float2bfloat16(e0 * rstd * w0 + b0);
            if (lane < 32)
                XS[t][64 + lane] = __float2bfloat16(e1 * rstd * w1_ + b1_);
        }
    }
    __syncthreads();                                   // bar0: XS ready

    // ---- own-strip A-frags, read ONCE (live through q/v/k GEMMs)
    bf16x8 ax0 = *(const bf16x8*)&XS[m0 + l15][koff];
    bf16x8 ax1 = *(const bf16x8*)&XS[m0 + l15][32 + koff];
    bf16x8 ax2 = *(const bf16x8*)&XS[m0 + l15][64 + koff];

    // ---- q-GEMM (strip-private) -> QB; qf preload (same wave, no barrier)
    __hip_bfloat16* QB = RB;                           // [112][104]
    #pragma unroll
    for (int nt = 0; nt < 6; ++nt) {
        f32x4 acc = {0.f, 0.f, 0.f, 0.f};
        acc = __builtin_amdgcn_mfma_f32_16x16x32_bf16(ax0,
              usews ? loadB_sw(wsb, nt * 3 + 0, lane)
                    : loadB_f32(qkv_w, (nt * 16 + l15) * 96 + koff), acc, 0, 0, 0);
        acc = __builtin_amdgcn_mfma_f32_16x16x32_bf16(ax1,
              usews ? loadB_sw(wsb, nt * 3 + 1, lane)
                    : loadB_f32(qkv_w, (nt * 16 + l15) * 96 + 32 + koff), acc, 0, 0, 0);
        acc = __builtin_amdgcn_mfma_f32_16x16x32_bf16(ax2,
              usews ? loadB_sw(wsb, nt * 3 + 2, lane)
                    : loadB_f32(qkv_w, (nt * 16 + l15) * 96 + 64 + koff), acc, 0, 0, 0);
        float bb = qkv_b[nt * 16 + l15];
        #pragma unroll
        for (int r = 0; r < 4; ++r) {
            float q = usews ? (acc[r] + bb * SCALE) : ((acc[r] + bb) * SCALE);
            QB[(m0 + drow + r) * 104 + nt * 16 + l15] = __float2bfloat16(q);
        }
    }
    bf16x8 qf0 = *(const bf16x8*)&QB[(m0 + l15) * 104 + koff];
    bf16x8 qf1 = *(const bf16x8*)&QB[(m0 + l15) * 104 + 32 + koff];
    bf16x8 qf2 = *(const bf16x8*)&QB[(m0 + l15) * 104 + 64 + koff];
    __syncthreads();                                   // bar1: QB dead -> vT

    // ---- vT tail zero (cols 98..135), then v-GEMM -> vT, k-GEMM -> K over XS
    __hip_bfloat16* vT = RB;                           // [96][136]
    for (int i = tid; i < 96 * 38; i += 448) {
        int r = i / 38, c = 98 + (i - r * 38);
        vT[r * 136 + c] = __float2bfloat16(0.f);
    }
    #pragma unroll
    for (int nt = 0; nt < 6; ++nt) {                   // V chunk (c=2)
        f32x4 acc = {0.f, 0.f, 0.f, 0.f};
        acc = __builtin_amdgcn_mfma_f32_16x16x32_bf16(ax0,
              usews ? loadB_sw(wsb, (12 + nt) * 3 + 0, lane)
                    : loadB_f32(qkv_w + 18432, (nt * 16 + l15) * 96 + koff), acc, 0, 0, 0);
        acc = __builtin_amdgcn_mfma_f32_16x16x32_bf16(ax1,
              usews ? loadB_sw(wsb, (12 + nt) * 3 + 1, lane)
                    : loadB_f32(qkv_w + 18432, (nt * 16 + l15) * 96 + 32 + koff), acc, 0, 0, 0);
        acc = __builtin_amdgcn_mfma_f32_16x16x32_bf16(ax2,
              usews ? loadB_sw(wsb, (12 + nt) * 3 + 2, lane)
                    : loadB_f32(qkv_w + 18432, (nt * 16 + l15) * 96 + 64 + koff), acc, 0, 0, 0);
        float bb = qkv_b[192 + nt * 16 + l15];
        unsigned int d0 = pk2(acc[0] + bb, acc[1] + bb);
        unsigned int d1 = pk2(acc[2] + bb, acc[3] + bb);
        int u0 = m0 + drow;
        if (u0 < NTOK) {
            unsigned int* p = (unsigned int*)&vT[(nt * 16 + l15) * 136 + u0];
            p[0] = d0;
            if (u0 + 2 < NTOK) p[1] = d1;
        }
    }
    #pragma unroll
    for (int nt = 0; nt < 6; ++nt) {                   // K chunk (c=1), in-place
        f32x4 acc = {0.f, 0.f, 0.f, 0.f};
        acc = __builtin_amdgcn_mfma_f32_16x16x32_bf16(ax0,
              usews ? loadB_sw(wsb, (6 + nt) * 3 + 0, lane)
                    : loadB_f32(qkv_w + 9216, (nt * 16 + l15) * 96 + koff), acc, 0, 0, 0);
        acc = __builtin_amdgcn_mfma_f32_16x16x32_bf16(ax1,
              usews ? loadB_sw(wsb, (6 + nt) * 3 + 1, lane)
                    : loadB_f32(qkv_w + 9216, (nt * 16 + l15) * 96 + 32 + koff), acc, 0, 0, 0);
        acc = __builtin_amdgcn_mfma_f32_16x16x32_bf16(ax2,
              usews ? loadB_sw(wsb, (6 + nt) * 3 + 2, lane)
                    : loadB_f32(qkv_w + 9216, (nt * 16 + l15) * 96 + 64 + koff), acc, 0, 0, 0);
        float bb = qkv_b[96 + nt * 16 + l15];
        #pragma unroll
        for (int r = 0; r < 4; ++r)
            XS[m0 + drow + r][nt * 16 + l15] = __float2bfloat16(acc[r] + bb);
    }
    __syncthreads();                                   // bar2: K + vT ready

    // ---- head loop (strip wv, h=0..2), fully wave-private, out in regs
    unsigned int po[3][4];
    #pragma unroll 1
    for (int h = 0; h < 3; ++h) {
        bf16x8 qh = (h == 0) ? qf0 : (h == 1) ? qf1 : qf2;
        f32x4 s[7];
        #pragma unroll
        for (int U = 0; U < 7; ++U) {
            bf16x8 ak = *(const bf16x8*)&XS[U * 16 + l15][h * 32 + koff];
            f32x4 z = {0.f, 0.f, 0.f, 0.f};
            s[U] = __builtin_amdgcn_mfma_f32_16x16x32_bf16(ak, qh, z, 0, 0, 0);
        }
        if (usews) {
            const __hip_bfloat16* bmb = biasMb + (((h * 7 + wv) * 7) << 8) + (lane << 2);
            #pragma unroll
            for (int U = 0; U < 7; ++U) {
                uint2 bv = *(const uint2*)(bmb + (U << 8));
                s[U][0] += bl16(bv.x); s[U][1] += bh16(bv.x);
                s[U][2] += bl16(bv.y); s[U][3] += bh16(bv.y);
            }
        } else {
            int tq = wv * 16 + l15; if (tq > 97) tq = 97;
            int pt = pcode(tq);
            #pragma unroll
            for (int U = 0; U < 7; ++U)
                #pragma unroll
                for (int r = 0; r < 4; ++r) {
                    int u = U * 16 + drow + r; if (u > 97) u = 97;
                    s[U][r] += rpb[(pt - pcode(u) + 253) * 3 + h];
                }
        }
        if (drow > 0) { s[6][0] = -1e30f; s[6][1] = -1e30f; }
        s[6][2] = -1e30f; s[6][3] = -1e30f;
        f32x4 sumv = {0.f, 0.f, 0.f, 0.f};
        #pragma unroll
        for (int U = 0; U < 7; ++U) {
            #pragma unroll
            for (int r = 0; r < 4; ++r) { s[U][r] = __expf(s[U][r]); sumv[r] += s[U][r]; }
        }
        float hs = sumv[0] + sumv[1] + sumv[2] + sumv[3];
        hs += __shfl_xor(hs, 16, 64);
        hs += __shfl_xor(hs, 32, 64);
        float inv = 1.f / hs;
        unsigned int dwl[7], dwh[7];
        #pragma unroll
        for (int U = 0; U < 7; ++U) {
            dwl[U] = pk2(s[U][0] * inv, s[U][1] * inv);
            dwh[U] = pk2(s[U][2] * inv, s[U][3] * inv);
        }
        // PV swapped: C[d][t] = mfma(A=vT-frag, B=P-frag)
        f32x4 o0 = {0.f, 0.f, 0.f, 0.f}, o1 = {0.f, 0.f, 0.f, 0.f};
        #pragma unroll
        for (int ks = 0; ks < 4; ++ks) {
            unsigned int D0, D1, D2, D3;
            if (ks < 3) {
                unsigned int e0 = __shfl((int)dwl[2 * ks], srcA, 64);
                unsigned int q0 = __shfl((int)dwl[2 * ks + 1], srcA, 64);
                unsigned int e1 = __shfl((int)dwh[2 * ks], srcA, 64);
                unsigned int q1 = __shfl((int)dwh[2 * ks + 1], srcA, 64);
                unsigned int e2 = __shfl((int)dwl[2 * ks], srcB, 64);
                unsigned int q2 = __shfl((int)dwl[2 * ks + 1], srcB, 64);
                unsigned int e3 = __shfl((int)dwh[2 * ks], srcB, 64);
                unsigned int q3 = __shfl((int)dwh[2 * ks + 1], srcB, 64);
                D0 = oddg ? q0 : e0; D1 = oddg ? q1 : e1;
                D2 = oddg ? q2 : e2; D3 = oddg ? q3 : e3;
            } else {
                unsigned int t0 = __shfl((int)dwl[6], srcA, 64);
                unsigned int t1 = __shfl((int)dwh[6], srcA, 64);
                unsigned int t2 = __shfl((int)dwl[6], srcB, 64);
                unsigned int t3 = __shfl((int)dwh[6], srcB, 64);
                D0 = (g < 2) ? t0 : 0u; D1 = (g < 2) ? t1 : 0u;
                D2 = (g < 2) ? t2 : 0u; D3 = (g < 2) ? t3 : 0u;
            }
            union { unsigned int d[4]; bf16x8 v; } af;
            af.d[0] = D0; af.d[1] = D1; af.d[2] = D2; af.d[3] = D3;
            bf16x8 va = *(const bf16x8*)&vT[(h * 32 + l15) * 136 + ks * 32 + koff];
            bf16x8 vb = *(const bf16x8*)&vT[(h * 32 + 16 + l15) * 136 + ks * 32 + koff];
            o0 = __builtin_amdgcn_mfma_f32_16x16x32_bf16(va, af.v, o0, 0, 0, 0);
            o1 = __builtin_amdgcn_mfma_f32_16x16x32_bf16(vb, af.v, o1, 0, 0, 0);
        }
        po[h][0] = pk2(o0[0], o0[1]); po[h][1] = pk2(o0[2], o0[3]);
        po[h][2] = pk2(o1[0], o1[1]); po[h][3] = pk2(o1[2], o1[3]);
    }

    // ---- proj A-frags in-wave (p-transform of each head's C-pair)
    union { unsigned int d[4]; bf16x8 v; } afO[3];
    #pragma unroll
    for (int h = 0; h < 3; ++h) {
        unsigned int e0 = __shfl((int)po[h][0], srcA, 64);
        unsigned int q0 = __shfl((int)po[h][2], srcA, 64);
        unsigned int e1 = __shfl((int)po[h][1], srcA, 64);
        unsigned int q1 = __shfl((int)po[h][3], srcA, 64);
        unsigned int e2 = __shfl((int)po[h][0], srcB, 64);
        unsigned int q2 = __shfl((int)po[h][2], srcB, 64);
        unsigned int e3 = __shfl((int)po[h][1], srcB, 64);
        unsigned int q3 = __shfl((int)po[h][3], srcB, 64);
        afO[h].d[0] = oddg ? q0 : e0;
        afO[h].d[1] = oddg ? q1 : e1;
        afO[h].d[2] = oddg ? q2 : e2;
        afO[h].d[3] = oddg ? q3 : e3;
    }

    // ---- proj GEMM + x residual -> res regs; LN2 stats on the fly
    float res[6][4];
    f32x4 sAcc = {0.f, 0.f, 0.f, 0.f}, sqAcc = {0.f, 0.f, 0.f, 0.f};
    #pragma unroll
    for (int nt = 0; nt < 6; ++nt) {
        f32x4 acc = {0.f, 0.f, 0.f, 0.f};
        #pragma unroll
        for (int h = 0; h < 3; ++h) {
            bf16x8 b = usews ? loadB_sw(wsb, FR_PROJ + nt * 3 + h, lane)
                             : loadB_f32(proj_w, (nt * 16 + l15) * 96 + h * 32 + koff);
            acc = __builtin_amdgcn_mfma_f32_16x16x32_bf16(afO[h].v, b, acc, 0, 0, 0);
        }
        float pb = proj_b[nt * 16 + l15];
        #pragma unroll
        for (int r = 0; r < 4; ++r) {
            int t = m0 + drow + r;
            float rv = (t < NTOK) ? (acc[r] + pb + x[rowbase[t] + nt * 16 + l15]) : 0.f;
            res[nt][r] = rv;
            sAcc[r] += rv; sqAcc[r] += rv * rv;
        }
    }
    float mean[4], rstd[4];
    #pragma unroll
    for (int r = 0; r < 4; ++r) {
        float s = sAcc[r], sq = sqAcc[r];
        #pragma unroll
        for (int m = 1; m < 16; m <<= 1) {
            s  += __shfl_xor(s, m, 64);
            sq += __shfl_xor(sq, m, 64);
        }
        mean[r] = s * (1.f / 96.f);
        float var = sq * (1.f / 96.f) - mean[r] * mean[r];
        rstd[r] = rsqrtf(var + 1e-5f);
    }
    __syncthreads();                                   // bar3: K + vT dead

    // ---- write XS2 (region A) + resB bf16 (region B), wave-private rows
    __hip_bfloat16* resB = RB;                         // [112][104]
    #pragma unroll
    for (int nt = 0; nt < 6; ++nt) {
        int cc = nt * 16 + l15;
        float w2_ = n2w[cc], b2_ = n2b[cc];
        #pragma unroll
        for (int r = 0; r < 4; ++r) {
            XS[m0 + drow + r][cc] =
                __float2bfloat16((res[nt][r] - mean[r]) * rstd[r] * w2_ + b2_);
            resB[(m0 + drow + r) * 104 + cc] = __float2bfloat16(res[nt][r]);
        }
    }

    // ---- MLP (wave-private): GEMM1-swapped -> GELU -> p-transform -> GEMM2
    bf16x8 xb0 = *(const bf16x8*)&XS[m0 + l15][koff];
    bf16x8 xb1 = *(const bf16x8*)&XS[m0 + l15][32 + koff];
    bf16x8 xb2 = *(const bf16x8*)&XS[m0 + l15][64 + koff];
    f32x4 yacc[6];
    #pragma unroll
    for (int nt = 0; nt < 6; ++nt) yacc[nt] = (f32x4){0.f, 0.f, 0.f, 0.f};

    #pragma unroll 1
    for (int hc = 0; hc < 6; ++hc) {
        #pragma unroll
        for (int p = 0; p < 2; ++p) {
            f32x4 s0 = {0.f, 0.f, 0.f, 0.f}, s1v = {0.f, 0.f, 0.f, 0.f};
            #pragma unroll
            for (int ks = 0; ks < 3; ++ks) {
                bf16x8 xb = (ks == 0) ? xb0 : (ks == 1) ? xb1 : xb2;
                bf16x8 aw0 = usews ? loadB_sw(wsb, FR_FC1 + (hc * 4 + 2 * p) * 3 + ks, lane)
                                   : loadB_f32(w1, (hc * 64 + 2 * p * 16 + l15) * 96 + ks * 32 + koff);
                bf16x8 aw1 = usews ? loadB_sw(wsb, FR_FC1 + (hc * 4 + 2 * p + 1) * 3 + ks, lane)
                                   : loadB_f32(w1, (hc * 64 + (2 * p + 1) * 16 + l15) * 96 + ks * 32 + koff);
                s0  = __builtin_amdgcn_mfma_f32_16x16x32_bf16(aw0, xb, s0, 0, 0, 0);
                s1v = __builtin_amdgcn_mfma_f32_16x16x32_bf16(aw1, xb, s1v, 0, 0, 0);
            }
            f32x4 bv0 = *(const f32x4*)&b1[hc * 64 + 2 * p * 16 + drow];
            f32x4 bv1 = *(const f32x4*)&b1[hc * 64 + (2 * p + 1) * 16 + drow];
            unsigned int dl0 = pk2(gelu(s0[0] + bv0[0]), gelu(s0[1] + bv0[1]));
            unsigned int dh0 = pk2(gelu(s0[2] + bv0[2]), gelu(s0[3] + bv0[3]));
            unsigned int dl1 = pk2(gelu(s1v[0] + bv1[0]), gelu(s1v[1] + bv1[1]));
            unsigned int dh1 = pk2(gelu(s1v[2] + bv1[2]), gelu(s1v[3] + bv1[3]));

            unsigned int e0 = __shfl((int)dl0, srcA, 64);
            unsigned int q0 = __shfl((int)dl1, srcA, 64);
            unsigned int e1 = __shfl((int)dh0, srcA, 64);
            unsigned int q1 = __shfl((int)dh1, srcA, 64);
            unsigned int e2 = __shfl((int)dl0, srcB, 64);
            unsigned int q2 = __shfl((int)dl1, srcB, 64);
            unsigned int e3 = __shfl((int)dh0, srcB, 64);
            unsigned int q3 = __shfl((int)dh1, srcB, 64);
            union { unsigned int d[4]; bf16x8 v; } af;
            af.d[0] = oddg ? q0 : e0;
            af.d[1] = oddg ? q1 : e1;
            af.d[2] = oddg ? q2 : e2;
            af.d[3] = oddg ? q3 : e3;
            #pragma unroll
            for (int nt = 0; nt < 6; ++nt) {
                bf16x8 bw = usews ? loadB_sw(wsb, FR_FC2 + hc * 12 + nt * 2 + p, lane)
                                  : loadB_f32(w2, (nt * 16 + l15) * 384 + hc * 64 + p * 32 + koff);
                yacc[nt] = __builtin_amdgcn_mfma_f32_16x16x32_bf16(af.v, bw, yacc[nt], 0, 0, 0);
            }
        }
    }

    // ---- final: out = resB + y + b2 (wave-private, 64B segments)
    #pragma unroll
    for (int nt = 0; nt < 6; ++nt) {
        float bb2 = b2[nt * 16 + l15];
        #pragma unroll
        for (int r = 0; r < 4; ++r) {
            int t = m0 + drow + r;
            if (t < NTOK) {
                float rv = __bfloat162float(resB[t * 104 + nt * 16 + l15]);
                out[rowbase[t] + nt * 16 + l15] = rv + yacc[nt][r] + bb2;
            }
        }
    }
}

extern "C" void kernel_launch(void* const* d_in, const int* in_sizes, int n_in,
                              void* d_out, int out_size, void* d_ws, size_t ws_size,
                              hipStream_t stream) {
    const float* x      = (const float*)d_in[0];
    const float* n1w    = (const float*)d_in[1];
    const float* n1b    = (const float*)d_in[2];
    const float* qkv_w  = (const float*)d_in[3];
    const float* qkv_b  = (const float*)d_in[4];
    const float* proj_w = (const float*)d_in[5];
    const float* proj_b = (const float*)d_in[6];
    const float* rpb    = (const float*)d_in[7];
    const float* n2w    = (const float*)d_in[8];
    const float* n2b    = (const float*)d_in[9];
    const float* fc1_w  = (const float*)d_in[10];
    const float* fc1_b  = (const float*)d_in[11];
    const float* fc2_w  = (const float*)d_in[12];
    const float* fc2_b  = (const float*)d_in[13];
    float* out = (float*)d_out;

    const int usews = (ws_size >= (size_t)WS_NEED) ? 1 : 0;
    __hip_bfloat16* wsb = (__hip_bfloat16*)d_ws;
    __hip_bfloat16* biasMb = (__hip_bfloat16*)((char*)d_ws + WS_BIASM_BYTE);

    if (usews)
        prep_kernel<<<(WS_BF16_N + 37632 + 255) / 256, 256, 0, stream>>>(
            qkv_w, proj_w, fc1_w, fc2_w, rpb, wsb, biasMb);

    fused_kernel<<<2048, 448, 0, stream>>>(x, n1w, n1b, qkv_w, qkv_b,
                                           proj_w, proj_b, rpb,
                                           n2w, n2b, fc1_w, fc1_b, fc2_w, fc2_b,
                                           wsb, biasMb, usews, out);
}

// Round 11
// 404.167 us; speedup vs baseline: 1.0214x; 1.0214x over previous
//
#include <hip/hip_runtime.h>
#include <hip/hip_bf16.h>
#include <math.h>

// Swin Transformer 3D block, MI355X (gfx950).  R11: strip-ownership fused,
// spill-free. vs R10: __launch_bounds__(448,4) (VGPR<=128), head loop FULLY
// unrolled (no runtime-indexed register arrays -> no scratch demotion),
// res kept in registers (resB LDS bounce removed).
// Wave s owns token strip s end-to-end. 4 barriers. LDS 49.4 KB.

#define NTOK 98
#define SCALE 0.17677669529663687f

// fragment ids (x512 elems): qkv 0..53, proj 54..71, fc1 72..143, fc2 144..215
#define FR_PROJ 54
#define FR_FC1  72
#define FR_FC2  144
#define WS_BF16_N 110592
#define WS_BIASM_BYTE 221184
#define WS_NEED   296448

typedef __attribute__((ext_vector_type(8))) short bf16x8;
typedef __attribute__((ext_vector_type(4))) float f32x4;

__device__ __forceinline__ int row_of(int wid, int t) {
    int b = wid >> 8, rem = wid & 255;
    int d0 = rem >> 6, h0 = (rem >> 3) & 7, w0 = rem & 7;
    int td = t / 49, tr = t % 49, th = tr / 7, tw = tr % 7;
    int dd = d0 * 2 + td, hh = h0 * 7 + th, ww = w0 * 7 + tw;
    return ((b * 8 + dd) * 56 + hh) * 56 + ww;
}

__device__ __forceinline__ int pcode(int t) {
    int a = t / 49, r = t - 49 * a, b = r / 7, c = r - 7 * b;
    return a * 169 + b * 13 + c;
}

__device__ __forceinline__ unsigned short f2bfu(float f) {
    __hip_bfloat16 h = __float2bfloat16(f);
    unsigned short u; __builtin_memcpy(&u, &h, 2); return u;
}
__device__ __forceinline__ unsigned int pk2(float lo, float hi) {
    return (unsigned int)f2bfu(lo) | ((unsigned int)f2bfu(hi) << 16);
}
__device__ __forceinline__ float bl16(unsigned int u) {
    union { unsigned int i; float f; } c; c.i = u << 16; return c.f;
}
__device__ __forceinline__ float bh16(unsigned int u) {
    union { unsigned int i; float f; } c; c.i = u & 0xffff0000u; return c.f;
}
__device__ __forceinline__ bf16x8 loadB_sw(const __hip_bfloat16* wsb, int frag, int lane) {
    return *(const bf16x8*)(wsb + (frag << 9) + (lane << 3));
}
__device__ __forceinline__ bf16x8 loadB_f32(const float* wf, int idx) {
    bf16x8 r;
    #pragma unroll
    for (int j = 0; j < 8; ++j) r[j] = (short)f2bfu(wf[idx + j]);
    return r;
}
__device__ __forceinline__ float gelu(float v) {
    return 0.5f * v * (1.f + erff(v * 0.70710678118654752f));
}

// ---------------------------------------------------------------- prep
__global__ __launch_bounds__(256) void prep_kernel(
    const float* __restrict__ qkv_w, const float* __restrict__ proj_w,
    const float* __restrict__ fc1_w, const float* __restrict__ fc2_w,
    const float* __restrict__ rpb,
    __hip_bfloat16* __restrict__ wsb, __hip_bfloat16* __restrict__ biasMb)
{
    int i = blockIdx.x * 256 + threadIdx.x;
    if (i < WS_BF16_N) {
        int f = i >> 9, lane = (i >> 3) & 63, j = i & 7;
        int l15 = lane & 15, g = lane >> 4;
        float v;
        if (f < FR_PROJ) {
            int ks = f % 3, nt = (f / 3) % 6, c = f / 18;
            v = qkv_w[(c * 96 + nt * 16 + l15) * 96 + ks * 32 + g * 8 + j];
            if (c == 0) v *= SCALE;
        } else if (f < FR_FC1) {
            int f2 = f - FR_PROJ, ks = f2 % 3, nt = f2 / 3;
            v = proj_w[(nt * 16 + l15) * 96 + ks * 32 + g * 8 + j];
        } else if (f < FR_FC2) {
            int f2 = f - FR_FC1, ks = f2 % 3, nt = (f2 / 3) % 4, hc = f2 / 12;
            v = fc1_w[(hc * 64 + nt * 16 + l15) * 96 + ks * 32 + g * 8 + j];
        } else {
            int f2 = f - FR_FC2, p = f2 & 1, nt = (f2 >> 1) % 6, hc = f2 / 12;
            v = fc2_w[(nt * 16 + l15) * 384 + hc * 64 + p * 32 + g * 8 + j];
        }
        wsb[i] = __float2bfloat16(v);
    } else if (i < WS_BF16_N + 37632) {
        int j = i - WS_BF16_N;
        int r = j & 3, lane = (j >> 2) & 63;
        int rest = j >> 8;
        int U = rest % 7; rest /= 7;
        int Tt = rest % 7, h = rest / 7;
        int t = Tt * 16 + (lane & 15);              if (t > 97) t = 97;
        int u = U * 16 + ((lane >> 4) << 2) + r;    if (u > 97) u = 97;
        biasMb[j] = __float2bfloat16(rpb[(pcode(t) - pcode(u) + 253) * 3 + h]);
    }
}

// ---------------------------------------------------------------- fused block
__global__ __launch_bounds__(448, 4) void fused_kernel(
    const float* __restrict__ x,
    const float* __restrict__ n1w, const float* __restrict__ n1b,
    const float* __restrict__ qkv_w, const float* __restrict__ qkv_b,
    const float* __restrict__ proj_w, const float* __restrict__ proj_b,
    const float* __restrict__ rpb,
    const float* __restrict__ n2w, const float* __restrict__ n2b,
    const float* __restrict__ w1, const float* __restrict__ b1,
    const float* __restrict__ w2, const float* __restrict__ b2,
    const __hip_bfloat16* __restrict__ wsb, const __hip_bfloat16* __restrict__ biasMb,
    int usews,
    float* __restrict__ out)
{
    // Region A [0,23296): XS bf16[112][104] -> K (in-place) -> XS2
    // Region B [23296,49408): QB[112][104] -> vT[96][136]
    __shared__ __align__(16) unsigned char LB[49408];
    __shared__ int rowbase[NTOK];
    __hip_bfloat16 (*XS)[104] = (__hip_bfloat16 (*)[104])LB;
    __hip_bfloat16* RB = (__hip_bfloat16*)(LB + 23296);

    const int wid = blockIdx.x, tid = threadIdx.x;
    const int lane = tid & 63, wv = tid >> 6;       // 7 waves; wave = strip
    const int l15 = lane & 15;
    const int g = lane >> 4;
    const int koff = g * 8;
    const int drow = g * 4;
    const bool oddg = (g >> 1) & 1;
    const int srcA = l15 + ((g & 1) << 5);
    const int srcB = srcA + 16;
    const int m0 = wv * 16;

    for (int t = tid; t < NTOK; t += 448) rowbase[t] = row_of(wid, t) * 96;
    for (int i = tid; i < 14 * 104; i += 448) {     // zero XS pad rows 98..111
        int r = 98 + i / 104, c = i % 104;
        XS[r][c] = __float2bfloat16(0.f);
    }

    // ---- LN1 -> XS bf16 (one wave per token; 14 tokens/wave exact)
    {
        float w0 = n1w[lane], b0 = n1b[lane];
        float w1_ = (lane < 32) ? n1w[64 + lane] : 0.f;
        float b1_ = (lane < 32) ? n1b[64 + lane] : 0.f;
        for (int t = wv; t < NTOK; t += 7) {
            int base = row_of(wid, t) * 96;
            float v0 = x[base + lane];
            float v1 = (lane < 32) ? x[base + 64 + lane] : 0.f;
            float s = v0 + v1;
            #pragma unroll
            for (int m = 32; m; m >>= 1) s += __shfl_xor(s, m, 64);
            float mean = s * (1.f / 96.f);
            float e0 = v0 - mean;
            float e1 = (lane < 32) ? (v1 - mean) : 0.f;
            float ss = e0 * e0 + e1 * e1;
            #pragma unroll
            for (int m = 32; m; m >>= 1) ss += __shfl_xor(ss, m, 64);
            float rstd = rsqrtf(ss * (1.f / 96.f) + 1e-5f);
            XS[t][lane] = __float2bfloat16(e0 * rstd * w0 + b0);
            if (lane < 32)
                XS[t][64 + lane] = __float2bfloat16(e1 * rstd * w1_ + b1_);
        }
    }
    __syncthreads();                                   // bar0: XS ready

    // ---- own-strip A-frags, read ONCE (live through q/v/k GEMMs)
    bf16x8 ax0 = *(const bf16x8*)&XS[m0 + l15][koff];
    bf16x8 ax1 = *(const bf16x8*)&XS[m0 + l15][32 + koff];
    bf16x8 ax2 = *(const bf16x8*)&XS[m0 + l15][64 + koff];

    // ---- q-GEMM (strip-private) -> QB; qf preload (same wave, no barrier)
    __hip_bfloat16* QB = RB;                           // [112][104]
    #pragma unroll
    for (int nt = 0; nt < 6; ++nt) {
        f32x4 acc = {0.f, 0.f, 0.f, 0.f};
        acc = __builtin_amdgcn_mfma_f32_16x16x32_bf16(ax0,
              usews ? loadB_sw(wsb, nt * 3 + 0, lane)
                    : loadB_f32(qkv_w, (nt * 16 + l15) * 96 + koff), acc, 0, 0, 0);
        acc = __builtin_amdgcn_mfma_f32_16x16x32_bf16(ax1,
              usews ? loadB_sw(wsb, nt * 3 + 1, lane)
                    : loadB_f32(qkv_w, (nt * 16 + l15) * 96 + 32 + koff), acc, 0, 0, 0);
        acc = __builtin_amdgcn_mfma_f32_16x16x32_bf16(ax2,
              usews ? loadB_sw(wsb, nt * 3 + 2, lane)
                    : loadB_f32(qkv_w, (nt * 16 + l15) * 96 + 64 + koff), acc, 0, 0, 0);
        float bb = qkv_b[nt * 16 + l15];
        #pragma unroll
        for (int r = 0; r < 4; ++r) {
            float q = usews ? (acc[r] + bb * SCALE) : ((acc[r] + bb) * SCALE);
            QB[(m0 + drow + r) * 104 + nt * 16 + l15] = __float2bfloat16(q);
        }
    }
    bf16x8 qf0 = *(const bf16x8*)&QB[(m0 + l15) * 104 + koff];
    bf16x8 qf1 = *(const bf16x8*)&QB[(m0 + l15) * 104 + 32 + koff];
    bf16x8 qf2 = *(const bf16x8*)&QB[(m0 + l15) * 104 + 64 + koff];
    __syncthreads();                                   // bar1: QB dead -> vT

    // ---- vT tail zero (cols 98..135), then v-GEMM -> vT, k-GEMM -> K over XS
    __hip_bfloat16* vT = RB;                           // [96][136]
    for (int i = tid; i < 96 * 38; i += 448) {
        int r = i / 38, c = 98 + (i - r * 38);
        vT[r * 136 + c] = __float2bfloat16(0.f);
    }
    #pragma unroll
    for (int nt = 0; nt < 6; ++nt) {                   // V chunk (c=2)
        f32x4 acc = {0.f, 0.f, 0.f, 0.f};
        acc = __builtin_amdgcn_mfma_f32_16x16x32_bf16(ax0,
              usews ? loadB_sw(wsb, (12 + nt) * 3 + 0, lane)
                    : loadB_f32(qkv_w + 18432, (nt * 16 + l15) * 96 + koff), acc, 0, 0, 0);
        acc = __builtin_amdgcn_mfma_f32_16x16x32_bf16(ax1,
              usews ? loadB_sw(wsb, (12 + nt) * 3 + 1, lane)
                    : loadB_f32(qkv_w + 18432, (nt * 16 + l15) * 96 + 32 + koff), acc, 0, 0, 0);
        acc = __builtin_amdgcn_mfma_f32_16x16x32_bf16(ax2,
              usews ? loadB_sw(wsb, (12 + nt) * 3 + 2, lane)
                    : loadB_f32(qkv_w + 18432, (nt * 16 + l15) * 96 + 64 + koff), acc, 0, 0, 0);
        float bb = qkv_b[192 + nt * 16 + l15];
        unsigned int d0 = pk2(acc[0] + bb, acc[1] + bb);
        unsigned int d1 = pk2(acc[2] + bb, acc[3] + bb);
        int u0 = m0 + drow;
        if (u0 < NTOK) {
            unsigned int* p = (unsigned int*)&vT[(nt * 16 + l15) * 136 + u0];
            p[0] = d0;
            if (u0 + 2 < NTOK) p[1] = d1;
        }
    }
    #pragma unroll
    for (int nt = 0; nt < 6; ++nt) {                   // K chunk (c=1), in-place
        f32x4 acc = {0.f, 0.f, 0.f, 0.f};
        acc = __builtin_amdgcn_mfma_f32_16x16x32_bf16(ax0,
              usews ? loadB_sw(wsb, (6 + nt) * 3 + 0, lane)
                    : loadB_f32(qkv_w + 9216, (nt * 16 + l15) * 96 + koff), acc, 0, 0, 0);
        acc = __builtin_amdgcn_mfma_f32_16x16x32_bf16(ax1,
              usews ? loadB_sw(wsb, (6 + nt) * 3 + 1, lane)
                    : loadB_f32(qkv_w + 9216, (nt * 16 + l15) * 96 + 32 + koff), acc, 0, 0, 0);
        acc = __builtin_amdgcn_mfma_f32_16x16x32_bf16(ax2,
              usews ? loadB_sw(wsb, (6 + nt) * 3 + 2, lane)
                    : loadB_f32(qkv_w + 9216, (nt * 16 + l15) * 96 + 64 + koff), acc, 0, 0, 0);
        float bb = qkv_b[96 + nt * 16 + l15];
        #pragma unroll
        for (int r = 0; r < 4; ++r)
            XS[m0 + drow + r][nt * 16 + l15] = __float2bfloat16(acc[r] + bb);
    }
    __syncthreads();                                   // bar2: K + vT ready

    // ---- head loop (strip wv, h=0..2), FULLY UNROLLED, out in regs
    unsigned int po[3][4];
    #pragma unroll
    for (int h = 0; h < 3; ++h) {
        bf16x8 qh = (h == 0) ? qf0 : (h == 1) ? qf1 : qf2;
        f32x4 s[7];
        #pragma unroll
        for (int U = 0; U < 7; ++U) {
            bf16x8 ak = *(const bf16x8*)&XS[U * 16 + l15][h * 32 + koff];
            f32x4 z = {0.f, 0.f, 0.f, 0.f};
            s[U] = __builtin_amdgcn_mfma_f32_16x16x32_bf16(ak, qh, z, 0, 0, 0);
        }
        if (usews) {
            const __hip_bfloat16* bmb = biasMb + (((h * 7 + wv) * 7) << 8) + (lane << 2);
            #pragma unroll
            for (int U = 0; U < 7; ++U) {
                uint2 bv = *(const uint2*)(bmb + (U << 8));
                s[U][0] += bl16(bv.x); s[U][1] += bh16(bv.x);
                s[U][2] += bl16(bv.y); s[U][3] += bh16(bv.y);
            }
        } else {
            int tq = wv * 16 + l15; if (tq > 97) tq = 97;
            int pt = pcode(tq);
            #pragma unroll
            for (int U = 0; U < 7; ++U)
                #pragma unroll
                for (int r = 0; r < 4; ++r) {
                    int u = U * 16 + drow + r; if (u > 97) u = 97;
                    s[U][r] += rpb[(pt - pcode(u) + 253) * 3 + h];
                }
        }
        if (drow > 0) { s[6][0] = -1e30f; s[6][1] = -1e30f; }
        s[6][2] = -1e30f; s[6][3] = -1e30f;
        f32x4 sumv = {0.f, 0.f, 0.f, 0.f};
        #pragma unroll
        for (int U = 0; U < 7; ++U) {
            #pragma unroll
            for (int r = 0; r < 4; ++r) { s[U][r] = __expf(s[U][r]); sumv[r] += s[U][r]; }
        }
        float hs = sumv[0] + sumv[1] + sumv[2] + sumv[3];
        hs += __shfl_xor(hs, 16, 64);
        hs += __shfl_xor(hs, 32, 64);
        float inv = 1.f / hs;
        unsigned int dwl[7], dwh[7];
        #pragma unroll
        for (int U = 0; U < 7; ++U) {
            dwl[U] = pk2(s[U][0] * inv, s[U][1] * inv);
            dwh[U] = pk2(s[U][2] * inv, s[U][3] * inv);
        }
        // PV swapped: C[d][t] = mfma(A=vT-frag, B=P-frag)
        f32x4 o0 = {0.f, 0.f, 0.f, 0.f}, o1 = {0.f, 0.f, 0.f, 0.f};
        #pragma unroll
        for (int ks = 0; ks < 4; ++ks) {
            unsigned int D0, D1, D2, D3;
            if (ks < 3) {
                unsigned int e0 = __shfl((int)dwl[2 * ks], srcA, 64);
                unsigned int q0 = __shfl((int)dwl[2 * ks + 1], srcA, 64);
                unsigned int e1 = __shfl((int)dwh[2 * ks], srcA, 64);
                unsigned int q1 = __shfl((int)dwh[2 * ks + 1], srcA, 64);
                unsigned int e2 = __shfl((int)dwl[2 * ks], srcB, 64);
                unsigned int q2 = __shfl((int)dwl[2 * ks + 1], srcB, 64);
                unsigned int e3 = __shfl((int)dwh[2 * ks], srcB, 64);
                unsigned int q3 = __shfl((int)dwh[2 * ks + 1], srcB, 64);
                D0 = oddg ? q0 : e0; D1 = oddg ? q1 : e1;
                D2 = oddg ? q2 : e2; D3 = oddg ? q3 : e3;
            } else {
                unsigned int t0 = __shfl((int)dwl[6], srcA, 64);
                unsigned int t1 = __shfl((int)dwh[6], srcA, 64);
                unsigned int t2 = __shfl((int)dwl[6], srcB, 64);
                unsigned int t3 = __shfl((int)dwh[6], srcB, 64);
                D0 = (g < 2) ? t0 : 0u; D1 = (g < 2) ? t1 : 0u;
                D2 = (g < 2) ? t2 : 0u; D3 = (g < 2) ? t3 : 0u;
            }
            union { unsigned int d[4]; bf16x8 v; } af;
            af.d[0] = D0; af.d[1] = D1; af.d[2] = D2; af.d[3] = D3;
            bf16x8 va = *(const bf16x8*)&vT[(h * 32 + l15) * 136 + ks * 32 + koff];
            bf16x8 vb = *(const bf16x8*)&vT[(h * 32 + 16 + l15) * 136 + ks * 32 + koff];
            o0 = __builtin_amdgcn_mfma_f32_16x16x32_bf16(va, af.v, o0, 0, 0, 0);
            o1 = __builtin_amdgcn_mfma_f32_16x16x32_bf16(vb, af.v, o1, 0, 0, 0);
        }
        po[h][0] = pk2(o0[0], o0[1]); po[h][1] = pk2(o0[2], o0[3]);
        po[h][2] = pk2(o1[0], o1[1]); po[h][3] = pk2(o1[2], o1[3]);
    }

    // ---- proj A-frags in-wave (p-transform of each head's C-pair)
    union { unsigned int d[4]; bf16x8 v; } afO[3];
    #pragma unroll
    for (int h = 0; h < 3; ++h) {
        unsigned int e0 = __shfl((int)po[h][0], srcA, 64);
        unsigned int q0 = __shfl((int)po[h][2], srcA, 64);
        unsigned int e1 = __shfl((int)po[h][1], srcA, 64);
        unsigned int q1 = __shfl((int)po[h][3], srcA, 64);
        unsigned int e2 = __shfl((int)po[h][0], srcB, 64);
        unsigned int q2 = __shfl((int)po[h][2], srcB, 64);
        unsigned int e3 = __shfl((int)po[h][1], srcB, 64);
        unsigned int q3 = __shfl((int)po[h][3], srcB, 64);
        afO[h].d[0] = oddg ? q0 : e0;
        afO[h].d[1] = oddg ? q1 : e1;
        afO[h].d[2] = oddg ? q2 : e2;
        afO[h].d[3] = oddg ? q3 : e3;
    }

    // ---- proj GEMM + x residual -> res regs; LN2 stats on the fly
    float res[6][4];
    f32x4 sAcc = {0.f, 0.f, 0.f, 0.f}, sqAcc = {0.f, 0.f, 0.f, 0.f};
    #pragma unroll
    for (int nt = 0; nt < 6; ++nt) {
        f32x4 acc = {0.f, 0.f, 0.f, 0.f};
        #pragma unroll
        for (int h = 0; h < 3; ++h) {
            bf16x8 b = usews ? loadB_sw(wsb, FR_PROJ + nt * 3 + h, lane)
                             : loadB_f32(proj_w, (nt * 16 + l15) * 96 + h * 32 + koff);
            acc = __builtin_amdgcn_mfma_f32_16x16x32_bf16(afO[h].v, b, acc, 0, 0, 0);
        }
        float pb = proj_b[nt * 16 + l15];
        #pragma unroll
        for (int r = 0; r < 4; ++r) {
            int t = m0 + drow + r;
            float rv = (t < NTOK) ? (acc[r] + pb + x[rowbase[t] + nt * 16 + l15]) : 0.f;
            res[nt][r] = rv;
            sAcc[r] += rv; sqAcc[r] += rv * rv;
        }
    }
    float mean[4], rstd[4];
    #pragma unroll
    for (int r = 0; r < 4; ++r) {
        float s = sAcc[r], sq = sqAcc[r];
        #pragma unroll
        for (int m = 1; m < 16; m <<= 1) {
            s  += __shfl_xor(s, m, 64);
            sq += __shfl_xor(sq, m, 64);
        }
        mean[r] = s * (1.f / 96.f);
        float var = sq * (1.f / 96.f) - mean[r] * mean[r];
        rstd[r] = rsqrtf(var + 1e-5f);
    }
    __syncthreads();                                   // bar3: K + vT dead

    // ---- write XS2 (region A), wave-private rows
    #pragma unroll
    for (int nt = 0; nt < 6; ++nt) {
        int cc = nt * 16 + l15;
        float w2_ = n2w[cc], b2_ = n2b[cc];
        #pragma unroll
        for (int r = 0; r < 4; ++r)
            XS[m0 + drow + r][cc] =
                __float2bfloat16((res[nt][r] - mean[r]) * rstd[r] * w2_ + b2_);
    }

    // ---- MLP (wave-private): GEMM1-swapped -> GELU -> p-transform -> GEMM2
    bf16x8 xb0 = *(const bf16x8*)&XS[m0 + l15][koff];
    bf16x8 xb1 = *(const bf16x8*)&XS[m0 + l15][32 + koff];
    bf16x8 xb2 = *(const bf16x8*)&XS[m0 + l15][64 + koff];
    f32x4 yacc[6];
    #pragma unroll
    for (int nt = 0; nt < 6; ++nt) yacc[nt] = (f32x4){0.f, 0.f, 0.f, 0.f};

    #pragma unroll 1
    for (int hc = 0; hc < 6; ++hc) {
        #pragma unroll
        for (int p = 0; p < 2; ++p) {
            f32x4 s0 = {0.f, 0.f, 0.f, 0.f}, s1v = {0.f, 0.f, 0.f, 0.f};
            #pragma unroll
            for (int ks = 0; ks < 3; ++ks) {
                bf16x8 xb = (ks == 0) ? xb0 : (ks == 1) ? xb1 : xb2;
                bf16x8 aw0 = usews ? loadB_sw(wsb, FR_FC1 + (hc * 4 + 2 * p) * 3 + ks, lane)
                                   : loadB_f32(w1, (hc * 64 + 2 * p * 16 + l15) * 96 + ks * 32 + koff);
                bf16x8 aw1 = usews ? loadB_sw(wsb, FR_FC1 + (hc * 4 + 2 * p + 1) * 3 + ks, lane)
                                   : loadB_f32(w1, (hc * 64 + (2 * p + 1) * 16 + l15) * 96 + ks * 32 + koff);
                s0  = __builtin_amdgcn_mfma_f32_16x16x32_bf16(aw0, xb, s0, 0, 0, 0);
                s1v = __builtin_amdgcn_mfma_f32_16x16x32_bf16(aw1, xb, s1v, 0, 0, 0);
            }
            f32x4 bv0 = *(const f32x4*)&b1[hc * 64 + 2 * p * 16 + drow];
            f32x4 bv1 = *(const f32x4*)&b1[hc * 64 + (2 * p + 1) * 16 + drow];
            unsigned int dl0 = pk2(gelu(s0[0] + bv0[0]), gelu(s0[1] + bv0[1]));
            unsigned int dh0 = pk2(gelu(s0[2] + bv0[2]), gelu(s0[3] + bv0[3]));
            unsigned int dl1 = pk2(gelu(s1v[0] + bv1[0]), gelu(s1v[1] + bv1[1]));
            unsigned int dh1 = pk2(gelu(s1v[2] + bv1[2]), gelu(s1v[3] + bv1[3]));

            unsigned int e0 = __shfl((int)dl0, srcA, 64);
            unsigned int q0 = __shfl((int)dl1, srcA, 64);
            unsigned int e1 = __shfl((int)dh0, srcA, 64);
            unsigned int q1 = __shfl((int)dh1, srcA, 64);
            unsigned int e2 = __shfl((int)dl0, srcB, 64);
            unsigned int q2 = __shfl((int)dl1, srcB, 64);
            unsigned int e3 = __shfl((int)dh0, srcB, 64);
            unsigned int q3 = __shfl((int)dh1, srcB, 64);
            union { unsigned int d[4]; bf16x8 v; } af;
            af.d[0] = oddg ? q0 : e0;
            af.d[1] = oddg ? q1 : e1;
            af.d[2] = oddg ? q2 : e2;
            af.d[3] = oddg ? q3 : e3;
            #pragma unroll
            for (int nt = 0; nt < 6; ++nt) {
                bf16x8 bw = usews ? loadB_sw(wsb, FR_FC2 + hc * 12 + nt * 2 + p, lane)
                                  : loadB_f32(w2, (nt * 16 + l15) * 384 + hc * 64 + p * 32 + koff);
                yacc[nt] = __builtin_amdgcn_mfma_f32_16x16x32_bf16(af.v, bw, yacc[nt], 0, 0, 0);
            }
        }
    }

    // ---- final: out = res + y + b2 (wave-private, 64B segments)
    #pragma unroll
    for (int nt = 0; nt < 6; ++nt) {
        float bb2 = b2[nt * 16 + l15];
        #pragma unroll
        for (int r = 0; r < 4; ++r) {
            int t = m0 + drow + r;
            if (t < NTOK)
                out[rowbase[t] + nt * 16 + l15] = res[nt][r] + yacc[nt][r] + bb2;
        }
    }
}

extern "C" void kernel_launch(void* const* d_in, const int* in_sizes, int n_in,
                              void* d_out, int out_size, void* d_ws, size_t ws_size,
                              hipStream_t stream) {
    const float* x      = (const float*)d_in[0];
    const float* n1w    = (const float*)d_in[1];
    const float* n1b    = (const float*)d_in[2];
    const float* qkv_w  = (const float*)d_in[3];
    const float* qkv_b  = (const float*)d_in[4];
    const float* proj_w = (const float*)d_in[5];
    const float* proj_b = (const float*)d_in[6];
    const float* rpb    = (const float*)d_in[7];
    const float* n2w    = (const float*)d_in[8];
    const float* n2b    = (const float*)d_in[9];
    const float* fc1_w  = (const float*)d_in[10];
    const float* fc1_b  = (const float*)d_in[11];
    const float* fc2_w  = (const float*)d_in[12];
    const float* fc2_b  = (const float*)d_in[13];
    float* out = (float*)d_out;

    const int usews = (ws_size >= (size_t)WS_NEED) ? 1 : 0;
    __hip_bfloat16* wsb = (__hip_bfloat16*)d_ws;
    __hip_bfloat16* biasMb = (__hip_bfloat16*)((char*)d_ws + WS_BIASM_BYTE);

    if (usews)
        prep_kernel<<<(WS_BF16_N + 37632 + 255) / 256, 256, 0, stream>>>(
            qkv_w, proj_w, fc1_w, fc2_w, rpb, wsb, biasMb);

    fused_kernel<<<2048, 448, 0, stream>>>(x, n1w, n1b, qkv_w, qkv_b,
                                           proj_w, proj_b, rpb,
                                           n2w, n2b, fc1_w, fc1_b, fc2_w, fc2_b,
                                           wsb, biasMb, usews, out);
}